// Round 4
// baseline (27290.329 us; speedup 1.0000x reference)
//
#include <hip/hip_runtime.h>
#include <hip/hip_bf16.h>

#define T_STEPS 2048
#define BATCH   256
#define DIN     16
#define KROW    296      // padded A row stride (bf16): 256 h + 16 x + 16 zero + 8 pad
#define NT_ALL  65       // 64 gate tiles + 1 output tile
#define KSTEPS  9        // K = 288 = 9 * 32
#define BBLK    16       // batch rows per block
#define NTHREADS 1024    // 16 waves on ONE CU: whole hidden dim, W in registers

#define WP_ELEMS (NT_ALL * KSTEPS * 64 * 8)
#define BIAS_OFF ((size_t)WP_ELEMS * 2)

typedef __attribute__((ext_vector_type(8))) short bf16x8;
typedef __attribute__((ext_vector_type(4))) float f32x4;

__device__ __forceinline__ float fast_sigmoid(float x) {
    return __builtin_amdgcn_rcpf(1.f + __expf(-x));
}
__device__ __forceinline__ float fast_tanh(float x) {
    return 1.f - 2.f * __builtin_amdgcn_rcpf(1.f + __expf(2.f * x));
}
__device__ __forceinline__ unsigned short bf16b(float v) {
    return __bfloat16_as_ushort(__float2bfloat16(v));
}

// Pack W into MFMA-B fragment order (identical to rounds 2-3, verified):
// Wp[((tt*9+kt)*64+lane)*8+e]; tile tt<64: gate=tt&3, jt=tt>>2, col n=lane&15
// -> W row gr = gate*256 + jt*16 + n; k: [0,256)=W_hh, [256,272)=W_ih, rest 0.
// tile 64: cols 0..2 = W_uvw rows, 3..5 = W_pqr rows, x-cols zero.
__global__ void pack_kernel(const float* __restrict__ W_ih, const float* __restrict__ W_hh,
                            const float* __restrict__ b_ih, const float* __restrict__ b_hh,
                            const float* __restrict__ W_uvw, const float* __restrict__ b_uvw,
                            const float* __restrict__ W_pqr, const float* __restrict__ b_pqr,
                            __hip_bfloat16* __restrict__ Wp, float* __restrict__ bias) {
    int idx = blockIdx.x * 256 + threadIdx.x;
    if (idx < WP_ELEMS) {
        int e   = idx & 7;
        int L   = (idx >> 3) & 63;
        int rem = idx >> 9;
        int kt  = rem % KSTEPS;
        int tt  = rem / KSTEPS;
        int n   = L & 15;
        int k   = kt * 32 + (L >> 4) * 8 + e;
        float v = 0.f;
        if (tt < 64) {
            int gr = (tt & 3) * 256 + (tt >> 2) * 16 + n;
            if (k < 256)       v = W_hh[gr * 256 + k];
            else if (k < 272)  v = W_ih[gr * 16 + (k - 256)];
        } else if (k < 256) {
            if (n < 3)      v = W_uvw[n * 256 + k];
            else if (n < 6) v = W_pqr[(n - 3) * 256 + k];
        }
        Wp[idx] = __float2bfloat16(v);
    }
    if (idx < NT_ALL * 16) {
        int tt = idx >> 4, n = idx & 15;
        float bv = 0.f;
        if (tt < 64) {
            int gr = (tt & 3) * 256 + (tt >> 2) * 16 + n;
            bv = b_ih[gr] + b_hh[gr];
        } else {
            if (n < 3)      bv = b_uvw[n];
            else if (n < 6) bv = b_pqr[n - 3];
        }
        bias[idx] = bv;
    }
}

// 16 persistent blocks, one per 16-row batch group; each block = 16 waves on
// one CU covering the WHOLE hidden dim (wave w: j-tile w, gates i/f/g/o =
// packed tiles 4w..4w+3, 144 W-VGPRs/lane held for the entire run). h lives in
// LDS, exchanged by ONE __syncthreads per step. c stays in registers (lane-
// local i/f/g/o epilogue). Wave 15 also computes the 6-col output tile from
// the same A fragments; wave 0 prefetches x_{t+1}.
__global__ __launch_bounds__(NTHREADS, 4) void lstm_kernel(
        const float* __restrict__ xs, const __hip_bfloat16* __restrict__ Wp,
        const float* __restrict__ bias, float* __restrict__ out) {
    __shared__ __hip_bfloat16 Abuf[2][BBLK][KROW];
    const int tid  = threadIdx.x;
    const int w    = tid >> 6;        // 0..15
    const int lane = tid & 63;
    const int g    = blockIdx.x;      // batch group 0..15
    const int arow = lane & 15;       // tile col (j low bits / out col)
    const int akc  = lane >> 4;       // 0..3

    // zero both A panels (h_{-1}=0, zero-pad K cols)
    for (int i = tid; i < 2 * BBLK * KROW; i += NTHREADS)
        ((__hip_bfloat16*)Abuf)[i] = __ushort_as_bfloat16(0);
    __syncthreads();

    // stage x_0 into panel 0 (wave 0: b=lane>>2, 4-float chunk ch=lane&3)
    if (w == 0) {
        int b = lane >> 2, ch = lane & 3;
        const float4 xv = *(const float4*)&xs[((size_t)0 * BATCH + g * BBLK + b) * DIN + (ch << 2)];
        unsigned int p0 = ((unsigned)bf16b(xv.y) << 16) | bf16b(xv.x);
        unsigned int p1 = ((unsigned)bf16b(xv.w) << 16) | bf16b(xv.z);
        *(uint2*)&Abuf[0][b][256 + (ch << 2)] = make_uint2(p0, p1);
    }

    // persistent W fragments (loaded once, live whole kernel)
    const bf16x8* Wf = (const bf16x8*)Wp;
    bf16x8 wfr[4][9];
    float bs[4];
    #pragma unroll
    for (int gi = 0; gi < 4; ++gi) {
        #pragma unroll
        for (int kt = 0; kt < KSTEPS; ++kt)
            wfr[gi][kt] = Wf[(((w << 2) + gi) * KSTEPS + kt) * 64 + lane];
        bs[gi] = bias[((w << 2) + gi) * 16 + arow];
    }
    bf16x8 wout[9];
    float bo = 0.f;
    if (w == 15) {
        #pragma unroll
        for (int kt = 0; kt < KSTEPS; ++kt) wout[kt] = Wf[(64 * KSTEPS + kt) * 64 + lane];
        bo = bias[64 * 16 + arow];
    }

    float cst[4] = {0.f, 0.f, 0.f, 0.f};

    for (int t = 0; t <= T_STEPS; ++t) {
        const int p  = t & 1;
        const int pn = p ^ 1;

        // issue x_{t+1} global load early (wave 0), lands during MFMA phase
        float4 xv;
        if (w == 0 && t + 1 < T_STEPS) {
            int b = lane >> 2, ch = lane & 3;
            xv = *(const float4*)&xs[((size_t)(t + 1) * BATCH + g * BBLK + b) * DIN + (ch << 2)];
        }

        __syncthreads();  // h_{t-1} + x_t writes into panel p are visible

        // A fragments for this wave (identical addresses across waves -> LDS
        // broadcast traffic; 2-way bank aliasing only, free)
        bf16x8 af[9];
        const __hip_bfloat16* ab = &Abuf[p][arow][akc * 8];
        #pragma unroll
        for (int kt = 0; kt < KSTEPS; ++kt) af[kt] = *(const bf16x8*)(ab + kt * 32);

        // ---- gates + recurrence (all 16 waves)
        if (t < T_STEPS) {
            f32x4 acc[4];
            #pragma unroll
            for (int gi = 0; gi < 4; ++gi) acc[gi] = (f32x4){bs[gi], bs[gi], bs[gi], bs[gi]};
            #pragma unroll
            for (int kt = 0; kt < KSTEPS; ++kt)
                #pragma unroll
                for (int gi = 0; gi < 4; ++gi)
                    acc[gi] = __builtin_amdgcn_mfma_f32_16x16x32_bf16(af[kt], wfr[gi][kt], acc[gi], 0, 0, 0);

            // lane-local activations; c persistent in regs
            #pragma unroll
            for (int r = 0; r < 4; ++r) {
                float iv = acc[0][r], fv = acc[1][r], gv = acc[2][r], ov = acc[3][r];
                float cn = fast_sigmoid(fv) * cst[r] + fast_sigmoid(iv) * fast_tanh(gv);
                cst[r] = cn;
                float hvf = fast_sigmoid(ov) * fast_tanh(cn);
                Abuf[pn][(akc << 2) + r][(w << 4) + arow] = __ushort_as_bfloat16(bf16b(hvf));
            }
        }

        // ---- output tile: out[t-1] = h_{t-1} @ Wout (wave 15, same af)
        if (w == 15 && t >= 1) {
            f32x4 accO = (f32x4){bo, bo, bo, bo};
            #pragma unroll
            for (int kt = 0; kt < KSTEPS; ++kt)
                accO = __builtin_amdgcn_mfma_f32_16x16x32_bf16(af[kt], wout[kt], accO, 0, 0, 0);
            if (arow < 6) {
                #pragma unroll
                for (int r = 0; r < 4; ++r)
                    out[(((size_t)(t - 1) * BATCH) + g * BBLK + (akc << 2) + r) * 6 + arow] = accO[r];
            }
        }

        // ---- stage x_{t+1} into panel pn (wave 0)
        if (w == 0 && t + 1 < T_STEPS) {
            int b = lane >> 2, ch = lane & 3;
            unsigned int p0 = ((unsigned)bf16b(xv.y) << 16) | bf16b(xv.x);
            unsigned int p1 = ((unsigned)bf16b(xv.w) << 16) | bf16b(xv.z);
            *(uint2*)&Abuf[pn][b][256 + (ch << 2)] = make_uint2(p0, p1);
        }
    }
}

extern "C" void kernel_launch(void* const* d_in, const int* in_sizes, int n_in,
                              void* d_out, int out_size, void* d_ws, size_t ws_size,
                              hipStream_t stream) {
    const float* xs   = (const float*)d_in[0];
    const float* Wih  = (const float*)d_in[1];
    const float* Whh  = (const float*)d_in[2];
    const float* bih  = (const float*)d_in[3];
    const float* bhh  = (const float*)d_in[4];
    const float* Wuvw = (const float*)d_in[5];
    const float* buvw = (const float*)d_in[6];
    const float* Wpqr = (const float*)d_in[7];
    const float* bpqr = (const float*)d_in[8];
    float* out = (float*)d_out;

    __hip_bfloat16* Wp = (__hip_bfloat16*)d_ws;
    float* bias = (float*)((char*)d_ws + BIAS_OFF);

    pack_kernel<<<(WP_ELEMS + 255) / 256, 256, 0, stream>>>(
        Wih, Whh, bih, bhh, Wuvw, buvw, Wpqr, bpqr, Wp, bias);
    lstm_kernel<<<16, NTHREADS, 0, stream>>>(xs, Wp, bias, out);
}

// Round 5
// 5315.144 us; speedup vs baseline: 5.1344x; 5.1344x over previous
//
#include <hip/hip_runtime.h>
#include <hip/hip_bf16.h>

#define T_STEPS 2048
#define BATCH   256
#define DIN     16
#define KROW    296      // padded A row stride (bf16): 256 h + 16 x + 16 zero + 8 pad
#define NT_ALL  65       // 64 gate tiles + 1 output tile
#define KSTEPS  9        // K = 288 = 9 * 32
#define BBLK    16       // batch rows per block
#define NTHREADS 512     // 8 waves: 4 compute + 4 poll-helpers
#define GWORDS  1536     // remote words to gather: 3 slices * 512
#define SLOT_STRIDE 32768 // u64 per slot: 16 g * 4 q * 512

#define WP_ELEMS (NT_ALL * KSTEPS * 64 * 8)
#define BIAS_OFF ((size_t)WP_ELEMS * 2)                 // 599040
#define HX_OFF   (BIAS_OFF + (size_t)NT_ALL * 16 * 4)   // 603200 (8B aligned)
#define HX_BYTES ((size_t)2 * SLOT_STRIDE * 8)          // 524288

typedef __attribute__((ext_vector_type(8))) short bf16x8;
typedef __attribute__((ext_vector_type(4))) float f32x4;

__device__ __forceinline__ float fast_sigmoid(float x) {
    return __builtin_amdgcn_rcpf(1.f + __expf(-x));
}
__device__ __forceinline__ float fast_tanh(float x) {
    return 1.f - 2.f * __builtin_amdgcn_rcpf(1.f + __expf(2.f * x));
}
__device__ __forceinline__ unsigned short bf16b(float v) {
    return __bfloat16_as_ushort(__float2bfloat16(v));
}

// Pack W into MFMA-B fragment order (identical to rounds 2-4, verified).
__global__ void pack_kernel(const float* __restrict__ W_ih, const float* __restrict__ W_hh,
                            const float* __restrict__ b_ih, const float* __restrict__ b_hh,
                            const float* __restrict__ W_uvw, const float* __restrict__ b_uvw,
                            const float* __restrict__ W_pqr, const float* __restrict__ b_pqr,
                            __hip_bfloat16* __restrict__ Wp, float* __restrict__ bias) {
    int idx = blockIdx.x * 256 + threadIdx.x;
    if (idx < WP_ELEMS) {
        int e   = idx & 7;
        int L   = (idx >> 3) & 63;
        int rem = idx >> 9;
        int kt  = rem % KSTEPS;
        int tt  = rem / KSTEPS;
        int n   = L & 15;
        int k   = kt * 32 + (L >> 4) * 8 + e;
        float v = 0.f;
        if (tt < 64) {
            int gr = (tt & 3) * 256 + (tt >> 2) * 16 + n;
            if (k < 256)       v = W_hh[gr * 256 + k];
            else if (k < 272)  v = W_ih[gr * 16 + (k - 256)];
        } else if (k < 256) {
            if (n < 3)      v = W_uvw[n * 256 + k];
            else if (n < 6) v = W_pqr[(n - 3) * 256 + k];
        }
        Wp[idx] = __float2bfloat16(v);
    }
    if (idx < NT_ALL * 16) {
        int tt = idx >> 4, n = idx & 15;
        float bv = 0.f;
        if (tt < 64) {
            int gr = (tt & 3) * 256 + (tt >> 2) * 16 + n;
            bv = b_ih[gr] + b_hh[gr];
        } else {
            if (n < 3)      bv = b_uvw[n];
            else if (n < 6) bv = b_pqr[n - 3];
        }
        bias[idx] = bv;
    }
}

// 64 persistent blocks: q = bIdx>>4 (64-j slice), g = bIdx&15 (16 batch rows).
// 8 waves: waves 0-3 compute (wave w: j-tile q*4+w, W register-resident);
// wave 4: x prefetch + out tile (q==0); waves 5-7 add poll bandwidth.
// Exchange: self-validating u64 {tag32, 2xbf16}; ALL 512 threads poll 3
// INDEPENDENT words each (unconditional parallel reissue -> one sweep = one
// L3 latency, vs round 3's 5 serialized loads = 5x). One barrier per step.
__global__ __launch_bounds__(NTHREADS, 2) void lstm_kernel(
        const float* __restrict__ xs, const __hip_bfloat16* __restrict__ Wp,
        const float* __restrict__ bias, unsigned long long* __restrict__ Hx,
        float* __restrict__ out) {
    __shared__ __hip_bfloat16 Abuf[2][BBLK][KROW];
    const int tid  = threadIdx.x;
    const int w    = tid >> 6;        // 0..7
    const int lane = tid & 63;
    const int q    = blockIdx.x >> 4; // hidden slice 0..3
    const int g    = blockIdx.x & 15; // batch group 0..15
    const int arow = lane & 15;
    const int akc  = lane >> 4;

    // zero both A panels
    for (int i = tid; i < 2 * BBLK * KROW; i += NTHREADS)
        ((__hip_bfloat16*)Abuf)[i] = __ushort_as_bfloat16(0);
    __syncthreads();

    // stage x_0 into panel 0
    if (w == 4) {
        int b = lane >> 2, ch = lane & 3;
        const float4 xv = *(const float4*)&xs[((size_t)0 * BATCH + g * BBLK + b) * DIN + (ch << 2)];
        unsigned int p0 = ((unsigned)bf16b(xv.y) << 16) | bf16b(xv.x);
        unsigned int p1 = ((unsigned)bf16b(xv.w) << 16) | bf16b(xv.z);
        *(uint2*)&Abuf[0][b][256 + (ch << 2)] = make_uint2(p0, p1);
    }

    // persistent W fragments (waves 0-3; register/AGPR-resident all run)
    const bf16x8* Wf = (const bf16x8*)Wp;
    bf16x8 wfr[4][9];
    float bs[4] = {0.f, 0.f, 0.f, 0.f};
    if (w < 4) {
        int jt = q * 4 + w;
        #pragma unroll
        for (int gi = 0; gi < 4; ++gi) {
            #pragma unroll
            for (int kt = 0; kt < KSTEPS; ++kt)
                wfr[gi][kt] = Wf[(((jt << 2) + gi) * KSTEPS + kt) * 64 + lane];
            bs[gi] = bias[((jt << 2) + gi) * 16 + arow];
        }
    }
    bf16x8 wout[9];
    float bo = 0.f;
    if (w == 4 && q == 0) {
        #pragma unroll
        for (int kt = 0; kt < KSTEPS; ++kt) wout[kt] = Wf[(64 * KSTEPS + kt) * 64 + lane];
        bo = bias[64 * 16 + arow];
    }

    // per-thread poll targets: 3 independent words (f = tid, tid+512, tid+1024)
    int wo[3], lc[3], lb[3];
    #pragma unroll
    for (int k = 0; k < 3; ++k) {
        int f  = tid + (k << 9);
        int qq = f >> 9;
        int qr = qq + (qq >= q ? 1 : 0);
        int r  = f & 511;
        int wr = r >> 7, pr = (r >> 6) & 1, lr = r & 63;
        wo[k] = ((g << 2) + qr) * 512 + r;
        lc[k] = (qr << 6) + (wr << 4) + (lr & 15);
        lb[k] = ((lr >> 4) << 2) + (pr << 1);
    }

    // writer base: word = (g,q)*512 + w*128 + lane; rows pair0 at +0, pair1 +64
    unsigned long long* HWbase = Hx + ((g << 2) + q) * 512 + (w << 7) + lane;

    float cst[4] = {0.f, 0.f, 0.f, 0.f};

    for (int t = 0; t <= T_STEPS; ++t) {
        const int p  = t & 1;
        const int pn = p ^ 1;

        // issue x_{t+1} load early (wave 4), lands during the poll
        float4 xv;
        if (w == 4 && t + 1 < T_STEPS) {
            int b = lane >> 2, ch = lane & 3;
            xv = *(const float4*)&xs[((size_t)(t + 1) * BATCH + g * BBLK + b) * DIN + (ch << 2)];
        }

        // ---- poll remote words (tag == t, slot (t+1)&1); 3 parallel loads/sweep
        {
            const unsigned long long* HS = Hx + (size_t)((t + 1) & 1) * SLOT_STRIDE;
            const unsigned tagw = (unsigned)t;
            unsigned miss = 7;
            do {
                unsigned long long v0 = __hip_atomic_load(&HS[wo[0]], __ATOMIC_RELAXED, __HIP_MEMORY_SCOPE_AGENT);
                unsigned long long v1 = __hip_atomic_load(&HS[wo[1]], __ATOMIC_RELAXED, __HIP_MEMORY_SCOPE_AGENT);
                unsigned long long v2 = __hip_atomic_load(&HS[wo[2]], __ATOMIC_RELAXED, __HIP_MEMORY_SCOPE_AGENT);
                if ((miss & 1u) && (unsigned)(v0 >> 32) == tagw) {
                    unsigned lo = (unsigned)v0;
                    Abuf[p][lb[0]][lc[0]]     = __ushort_as_bfloat16((unsigned short)lo);
                    Abuf[p][lb[0] + 1][lc[0]] = __ushort_as_bfloat16((unsigned short)(lo >> 16));
                    miss &= ~1u;
                }
                if ((miss & 2u) && (unsigned)(v1 >> 32) == tagw) {
                    unsigned lo = (unsigned)v1;
                    Abuf[p][lb[1]][lc[1]]     = __ushort_as_bfloat16((unsigned short)lo);
                    Abuf[p][lb[1] + 1][lc[1]] = __ushort_as_bfloat16((unsigned short)(lo >> 16));
                    miss &= ~2u;
                }
                if ((miss & 4u) && (unsigned)(v2 >> 32) == tagw) {
                    unsigned lo = (unsigned)v2;
                    Abuf[p][lb[2]][lc[2]]     = __ushort_as_bfloat16((unsigned short)lo);
                    Abuf[p][lb[2] + 1][lc[2]] = __ushort_as_bfloat16((unsigned short)(lo >> 16));
                    miss &= ~4u;
                }
            } while (miss);
        }
        __syncthreads();

        // ---- gates + recurrence (waves 0-3)
        if (w < 4 && t < T_STEPS) {
            f32x4 acc[4];
            #pragma unroll
            for (int gi = 0; gi < 4; ++gi) acc[gi] = (f32x4){bs[gi], bs[gi], bs[gi], bs[gi]};
            const __hip_bfloat16* ab = &Abuf[p][arow][akc * 8];
            #pragma unroll
            for (int kt = 0; kt < KSTEPS; ++kt) {
                bf16x8 a = *(const bf16x8*)(ab + kt * 32);
                #pragma unroll
                for (int gi = 0; gi < 4; ++gi)
                    acc[gi] = __builtin_amdgcn_mfma_f32_16x16x32_bf16(a, wfr[gi][kt], acc[gi], 0, 0, 0);
            }

            // lane-local activations; publish each row-pair ASAP (early visibility)
            unsigned long long tg = ((unsigned long long)(unsigned)(t + 1)) << 32;
            unsigned long long* HD = HWbase + (size_t)(t & 1) * SLOT_STRIDE;
            unsigned short hb[4];
            #pragma unroll
            for (int pr = 0; pr < 2; ++pr) {
                #pragma unroll
                for (int rr = 0; rr < 2; ++rr) {
                    int r = pr * 2 + rr;
                    float iv = acc[0][r], fv = acc[1][r], gv = acc[2][r], ov = acc[3][r];
                    float cn = fast_sigmoid(fv) * cst[r] + fast_sigmoid(iv) * fast_tanh(gv);
                    cst[r] = cn;
                    hb[r] = bf16b(fast_sigmoid(ov) * fast_tanh(cn));
                }
                unsigned hp = ((unsigned)hb[pr * 2 + 1] << 16) | hb[pr * 2];
                __hip_atomic_store(HD + 64 * pr, tg | hp, __ATOMIC_RELAXED, __HIP_MEMORY_SCOPE_AGENT);
            }

            // own slice into next panel
            int col = (q << 6) + (w << 4) + arow;
            #pragma unroll
            for (int r = 0; r < 4; ++r)
                Abuf[pn][(akc << 2) + r][col] = __ushort_as_bfloat16(hb[r]);
        }

        // ---- out tile: out[t-1] from assembled h_{t-1} (wave 4 of q==0)
        if (w == 4 && q == 0 && t >= 1) {
            f32x4 accO = (f32x4){bo, bo, bo, bo};
            const __hip_bfloat16* ab = &Abuf[p][arow][akc * 8];
            #pragma unroll
            for (int kt = 0; kt < KSTEPS; ++kt) {
                bf16x8 a = *(const bf16x8*)(ab + kt * 32);
                accO = __builtin_amdgcn_mfma_f32_16x16x32_bf16(a, wout[kt], accO, 0, 0, 0);
            }
            if (arow < 6) {
                #pragma unroll
                for (int r = 0; r < 4; ++r)
                    out[(((size_t)(t - 1) * BATCH) + g * BBLK + (akc << 2) + r) * 6 + arow] = accO[r];
            }
        }

        // ---- stage x_{t+1} into panel pn (wave 4)
        if (w == 4 && t + 1 < T_STEPS) {
            int b = lane >> 2, ch = lane & 3;
            unsigned int p0 = ((unsigned)bf16b(xv.y) << 16) | bf16b(xv.x);
            unsigned int p1 = ((unsigned)bf16b(xv.w) << 16) | bf16b(xv.z);
            *(uint2*)&Abuf[pn][b][256 + (ch << 2)] = make_uint2(p0, p1);
        }
    }
}

extern "C" void kernel_launch(void* const* d_in, const int* in_sizes, int n_in,
                              void* d_out, int out_size, void* d_ws, size_t ws_size,
                              hipStream_t stream) {
    const float* xs   = (const float*)d_in[0];
    const float* Wih  = (const float*)d_in[1];
    const float* Whh  = (const float*)d_in[2];
    const float* bih  = (const float*)d_in[3];
    const float* bhh  = (const float*)d_in[4];
    const float* Wuvw = (const float*)d_in[5];
    const float* buvw = (const float*)d_in[6];
    const float* Wpqr = (const float*)d_in[7];
    const float* bpqr = (const float*)d_in[8];
    float* out = (float*)d_out;

    __hip_bfloat16* Wp = (__hip_bfloat16*)d_ws;
    float* bias = (float*)((char*)d_ws + BIAS_OFF);
    unsigned long long* Hx = (unsigned long long*)((char*)d_ws + HX_OFF);

    // tags must start at 0 (t=0 reads slot 1 expecting tag 0 with h=0 data)
    hipMemsetAsync(Hx, 0, HX_BYTES, stream);

    pack_kernel<<<(WP_ELEMS + 255) / 256, 256, 0, stream>>>(
        Wih, Whh, bih, bhh, Wuvw, buvw, Wpqr, bpqr, Wp, bias);
    lstm_kernel<<<64, NTHREADS, 0, stream>>>(xs, Wp, bias, Hx, out);
}